// Round 1
// 184.028 us; speedup vs baseline: 1.0425x; 1.0425x over previous
//
#include <hip/hip_runtime.h>
#include <math.h>

#define NPTS 16384
#define KN 32
#define C 256
#define NQ 8192              // 8 * 1024 queries
#define PF_ELEMS (NQ * C)

#define W1P_ELEMS (3 * 16 * 64 * 8)                 // 24576  (Ktiles=3, Ntiles=16)
#define W2P_ELEMS (8 * 16 * 64 * 8)                 // 65536  (Ktiles=8)
#define WP_ELEMS  (W1P_ELEMS + W2P_ELEMS)           // 90112 halves = 180224 B (16-aligned)
#define HSTR 264                                    // halves per H16 row

typedef _Float16 half8 __attribute__((ext_vector_type(8)));
typedef _Float16 half4v __attribute__((ext_vector_type(4)));
typedef _Float16 half2t __attribute__((ext_vector_type(2)));
typedef float f32x4 __attribute__((ext_vector_type(4)));

union H8u { half8 v; half2t h2[4]; };

__device__ __forceinline__ float fdot2f(half2t a, half2t b, float c) {
#if __has_builtin(__builtin_amdgcn_fdot2)
    return __builtin_amdgcn_fdot2(a, b, c, false);
#else
    return fmaf((float)a[1], (float)b[1], fmaf((float)a[0], (float)b[0], c));
#endif
}

// tanh-approx GeLU: max err ~3e-4.  y = x - x/(e^{2u}+1)
__device__ __forceinline__ float gelu_tanh(float x) {
    const float t  = x * x;
    const float p2 = fmaf(t, 0.0713548162726f, 1.59576912161f);
    const float e  = __expf(x * p2);
    return x - x * __builtin_amdgcn_rcpf(e + 1.0f);
}

__device__ __forceinline__ void stat8(const H8u& u, half2t ones, float& s, float& s2) {
    #pragma unroll
    for (int j = 0; j < 4; ++j) {
        s  = fdot2f(u.h2[j], ones, s);
        s2 = fdot2f(u.h2[j], u.h2[j], s2);
    }
}

__device__ __forceinline__ void norm_gelu8(H8u& u, const H8u& g, const H8u& be,
                                           half2t rsh, half2t nmuh) {
    #pragma unroll
    for (int j = 0; j < 4; ++j) {
        const half2t A = g.h2[j] * rsh;
        const half2t B = A * nmuh + be.h2[j];
        const half2t y = u.h2[j] * A + B;
        half2t o;
        o[0] = (_Float16)gelu_tanh((float)y[0]);
        o[1] = (_Float16)gelu_tanh((float)y[1]);
        u.h2[j] = o;
    }
}

__device__ __forceinline__ void norm8(H8u& u, const H8u& g, const H8u& be,
                                      half2t rsh, half2t nmuh) {
    #pragma unroll
    for (int j = 0; j < 4; ++j) {
        const half2t A = g.h2[j] * rsh;
        const half2t B = A * nmuh + be.h2[j];
        u.h2[j] = u.h2[j] * A + B;
    }
}

// ---------------------------------------------------------------------------
// Prep: pack W1 (91x256 + b1 folded at k=91, K-padded to 96) and W2 (256x256)
// into f16 fragment order; additionally pack xyz into float4 (x,y,z,|p|^2)
// with |p|^2 computed with the EXACT rounding sequence the encoder's ball
// query used previously (hoisted, bit-identical membership).
//   flat = ((kt*16 + nt)*64 + lane)*8 + j
//   k = kt*32 + (lane>>4)*8 + j ;  ch = nt*16 + (lane&15)
// ---------------------------------------------------------------------------
__global__ void prep_kernel(const float* __restrict__ W1,
                            const float* __restrict__ b1,
                            const float* __restrict__ W2,
                            const float* __restrict__ xyz,
                            _Float16* __restrict__ wp,
                            float4* __restrict__ xyzw) {
    const int idx = blockIdx.x * 256 + threadIdx.x;   // 0 .. 221183
    if (idx < 96 * 256) {
        const int k = idx >> 8, n = idx & 255;
        const float v = (k < 91) ? W1[k * 256 + n] : ((k == 91) ? b1[n] : 0.0f);
        const int kt = k >> 5, quad = (k >> 3) & 3, j = k & 7;
        const int nt = n >> 4, l15 = n & 15;
        wp[(((kt * 16 + nt) * 64) + quad * 16 + l15) * 8 + j] = (_Float16)v;
    } else if (idx < WP_ELEMS) {
        const int e = idx - 96 * 256;
        const int k = e >> 8, n = e & 255;
        const int kt = k >> 5, quad = (k >> 3) & 3, j = k & 7;
        const int nt = n >> 4, l15 = n & 15;
        wp[W1P_ELEMS + (((kt * 16 + nt) * 64) + quad * 16 + l15) * 8 + j] =
            (_Float16)W2[k * 256 + n];
    } else {
        const int pi = idx - WP_ELEMS;                // 0 .. 131071 (8*16384)
        const float px = xyz[pi * 3 + 0];
        const float py = xyz[pi * 3 + 1];
        const float pz = xyz[pi * 3 + 2];
        const float sp = __fadd_rn(__fadd_rn(__fmul_rn(px, px), __fmul_rn(py, py)),
                                   __fmul_rn(pz, pz));
        xyzw[pi] = make_float4(px, py, pz, sp);
    }
}

// ---------------------------------------------------------------------------
// Fused: ball-query + gather/posenc + MLP1(LN,GeLU) + MLP2(LN) + max.
// Round-14 (this session R0): VALU-cut round on the round-13 structure.
//  * weight loads via readfirstlane(w) uniform base + lane voffset (saddr
//    form, kills ~190 VALU/wave of 64-bit flat address arithmetic)
//  * ball query reads packed float4 (x,y,z,|p|^2): |p|^2 hoisted to prep
//    with identical rounding -> bit-identical membership; 3 strided dword
//    loads -> 1 coalesced 16B load; 5 fewer VALU/point
//  * branchless posenc: revolution-domain v_sin with +0.25 bias for cos,
//    exponent-add bit trick for 2^m/(2*pi); removes 8-lane divergence
//  * Xs/H16 de-overlaid (LDS 25.8KB, still 6 blocks/CU) -> overlay fence
//    barrier after GEMM1 removed
// Register budget per rounds 8-12: __launch_bounds__(256,6) is the spill-free
// sweet spot. No runtime-indexed private arrays (round-3 lesson).
// ---------------------------------------------------------------------------
__global__ void __launch_bounds__(256, 6)
encoder_fused(const float4* __restrict__ xyzw,
              const float* __restrict__ pf,
              const float* __restrict__ ctr,
              const float* __restrict__ g1, const float* __restrict__ be1,
              const float* __restrict__ b2, const float* __restrict__ g2,
              const float* __restrict__ be2,
              const _Float16* __restrict__ w1p,
              const _Float16* __restrict__ w2p,
              float* __restrict__ out0,      // patch_feature [8192][256]
              float* __restrict__ out1) {    // neighbor idx as float [8192][32]
    const int q = blockIdx.x;
    const int b = q >> 10;
    const int t = threadIdx.x;
    const int w = t >> 6;
    const int lane = t & 63;
    const int quad = lane >> 4;
    const int l15  = lane & 15;

    __shared__ __align__(16) _Float16 Xs[KN][104];                 // 6656
    __shared__ __align__(16) unsigned char H16raw[KN * HSTR * 2];  // 16896
    __shared__ __align__(16) _Float16 lnph[4 * 256];               // 2048: g1,be1,g2,be2
    __shared__ int nbr[KN];
    __shared__ int wcnt[2][4];

    _Float16 (*H16)[HSTR] = (_Float16(*)[HSTR])H16raw;
    _Float16* g1h  = lnph;
    _Float16* be1h = lnph + 256;
    _Float16* g2h  = lnph + 512;
    _Float16* be2h = lnph + 768;

    lnph[t]       = (_Float16)g1[t];
    lnph[256 + t] = (_Float16)be1[t];
    lnph[512 + t] = (_Float16)g2[t];
    lnph[768 + t] = (_Float16)be2[t];

    // ---- Phase 0: ball query (block-wide ordered compaction) ----
    // first-32-ascending == reference sort+slice; exact unfused fp32 formula
    // (|p|^2 precomputed in prep with the same rounding -> identical bits).
    const float4* xwb = xyzw + (size_t)b * NPTS;
    const float cx = ctr[q * 3 + 0];
    const float cy = ctr[q * 3 + 1];
    const float cz = ctr[q * 3 + 2];
    const float sc = __fadd_rn(__fadd_rn(__fmul_rn(cx, cx), __fmul_rn(cy, cy)),
                               __fmul_rn(cz, cz));

    int found = 0;
    int par = 0;
    for (int base = 0; base < NPTS; base += 256) {
        const int n = base + t;
        const float4 pw = xwb[n];
        const float dt = __fadd_rn(__fadd_rn(__fmul_rn(cx, pw.x), __fmul_rn(cy, pw.y)),
                                   __fmul_rn(cz, pw.z));
        const float sqr = __fsub_rn(__fadd_rn(sc, pw.w), __fmul_rn(2.0f, dt));
        const bool inball = (sqr <= 0.0625f);

        const unsigned long long m = __ballot(inball);
        if (lane == 0) wcnt[par][w] = (int)__popcll(m);
        __syncthreads();
        int pre = found;
        if (w > 0) pre += wcnt[par][0];
        if (w > 1) pre += wcnt[par][1];
        if (w > 2) pre += wcnt[par][2];
        const int tot = found + wcnt[par][0] + wcnt[par][1] + wcnt[par][2] + wcnt[par][3];
        const int pos = pre + (int)__popcll(m & ((1ull << lane) - 1ull));
        if (inball && pos < KN) nbr[pos] = n;
        found = tot;                  // block-uniform
        par ^= 1;
        if (found >= KN) break;
    }
    __syncthreads();                  // nbr visible to all
    const int count = (found < KN) ? found : KN;
    const int first = (count > 0) ? nbr[0] : NPTS;

    if (t < KN)
        out1[(size_t)q * KN + t] = (float)((t < count) ? nbr[t] : first);

    // ---- Phase 1: gather + rel + posenc into Xs (f16; k=91 is 1.0 for b1) ----
    {
        const int k  = t >> 3;
        const int tc = t & 7;
        const int nidx = (k < count) ? nbr[k] : first;
        const int n = (nidx < NPTS) ? nidx : NPTS - 1;   // JAX OOB gather clamp
        const float4 pw = xwb[n];
        const float rx = pw.x - cx;
        const float ry = pw.y - cy;
        const float rz = pw.z - cz;
        const float* pfr = pf + ((size_t)b * NPTS + n) * 64;

        const float4 f0 = *(const float4*)(pfr + tc * 8);
        const float4 f1 = *(const float4*)(pfr + tc * 8 + 4);
        half8 hv;
        hv[0] = (_Float16)f0.x; hv[1] = (_Float16)f0.y;
        hv[2] = (_Float16)f0.z; hv[3] = (_Float16)f0.w;
        hv[4] = (_Float16)f1.x; hv[5] = (_Float16)f1.y;
        hv[6] = (_Float16)f1.z; hv[7] = (_Float16)f1.w;
        *(half8*)&Xs[k][tc * 8] = hv;

        // branchless posenc: ch c = 64+cm; cm<3 -> raw rel; 3<=cm<27 ->
        // sin/cos(r * 2^m) via v_sin in revolutions (cos = sin(u+0.25));
        // cm==27 -> 1.0 (bias row); cm>27 -> 0.
        half4v ov;
        #pragma unroll
        for (int j = 0; j < 4; ++j) {
            const int cm = tc * 4 + j;          // 0..31
            const int jj = cm - 3;
            const int d  = jj >> 3;
            const int mm = jj & 7;
            const float rsel = (d == 0) ? rx : ((d == 1) ? ry : rz);
            // (1<<(mm&3)) / (2*pi) via exponent add on 0x3E22F983 (=1/2pi)
            const float f2 = __int_as_float(0x3E22F983 + ((mm & 3) << 23));
            const float arg = fmaf(rsel, f2, (mm >= 4) ? 0.25f : 0.0f);
#if __has_builtin(__builtin_amdgcn_sinf)
            const float sv = __builtin_amdgcn_sinf(arg);
#else
            const float sv = __sinf(arg * 6.2831853071795864f);
#endif
            float v = (cm < 3) ? ((cm == 0) ? rx : ((cm == 1) ? ry : rz)) : sv;
            v = (cm == 27) ? 1.0f : ((cm > 27) ? 0.0f : v);
            ov[j] = (_Float16)v;
        }
        *(half4v*)&Xs[k][64 + tc * 4] = ov;
    }
    __syncthreads();

    f32x4 acc[2][4];   // lane: ch=(w*4+nt)*16+quad*4+r, pt=mt*16+l15

    // uniform (SGPR) weight bases + per-lane voffset -> saddr-form loads
    const int wu = __builtin_amdgcn_readfirstlane(w);
    const _Float16* __restrict__ w1w = w1p + (size_t)(wu * 4) * 512;
    const _Float16* __restrict__ w2w = w2p + (size_t)(wu * 4) * 512;
    const int lo8 = lane * 8;

    // ---- GEMM1: W1^T as A, X as B  ->  acc (b1 via folded row) ----
    #pragma unroll
    for (int mt = 0; mt < 2; ++mt)
        #pragma unroll
        for (int nt = 0; nt < 4; ++nt)
            acc[mt][nt] = (f32x4){0.f, 0.f, 0.f, 0.f};

    #pragma unroll
    for (int kt = 0; kt < 3; ++kt) {
        const half8 x0 = *(const half8*)&Xs[l15][kt * 32 + quad * 8];
        const half8 x1 = *(const half8*)&Xs[16 + l15][kt * 32 + quad * 8];
        #pragma unroll
        for (int nt = 0; nt < 4; ++nt) {
            const half8 wf = *(const half8*)(w1w + (kt * 16 + nt) * 512 + lo8);
            acc[0][nt] = __builtin_amdgcn_mfma_f32_16x16x32_f16(wf, x0, acc[0][nt], 0, 0, 0);
            acc[1][nt] = __builtin_amdgcn_mfma_f32_16x16x32_f16(wf, x1, acc[1][nt], 0, 0, 0);
        }
    }

    // ---- C-store GEMM1: raw f16, 8 contiguous ds_write_b64 (acc dies here) ----
    // (Xs and H16 are separate buffers now: no overlay fence needed.)
    #pragma unroll
    for (int nt = 0; nt < 4; ++nt) {
        const int chb = (w * 4 + nt) * 16 + quad * 4;
        #pragma unroll
        for (int mt = 0; mt < 2; ++mt) {
            half4v h;
            #pragma unroll
            for (int r = 0; r < 4; ++r)
                h[r] = (_Float16)acc[mt][nt][r];
            *(half4v*)&H16[mt * 16 + l15][chb] = h;
        }
    }
    __syncthreads();

    const int row = t >> 3;         // LN ownership: thread = (row, octet p)
    const int p   = t & 7;          // owns cols [16p,16p+16) and [128+16p,+16)
    _Float16* hrow0 = &H16[row][16 * p];
    _Float16* hrow1 = &H16[row][128 + 16 * p];
    half2t ones;
    ones[0] = (_Float16)1.0f;
    ones[1] = (_Float16)1.0f;

    // ---- Phase 3: LN1 + GeLU, in place on H16 (round-8 scheme) ----
    {
        H8u u0, u1, u2, u3;
        u0.v = *(const half8*)hrow0;
        u1.v = *(const half8*)(hrow0 + 8);
        u2.v = *(const half8*)hrow1;
        u3.v = *(const half8*)(hrow1 + 8);

        float s = 0.0f, s2 = 0.0f;
        stat8(u0, ones, s, s2); stat8(u1, ones, s, s2);
        stat8(u2, ones, s, s2); stat8(u3, ones, s, s2);
        #pragma unroll
        for (int off = 1; off < 8; off <<= 1) {
            s  += __shfl_xor(s, off, 64);
            s2 += __shfl_xor(s2, off, 64);
        }
        const float mu  = s * (1.0f / 256.0f);
        const float var = fmaf(s2, 1.0f / 256.0f, -mu * mu);
        const float rs  = __builtin_amdgcn_rsqf(var + 1e-5f);
        half2t rsh, nmuh;
        rsh[0]  = (_Float16)rs;    rsh[1]  = (_Float16)rs;
        nmuh[0] = (_Float16)(-mu); nmuh[1] = (_Float16)(-mu);

        H8u gA0, gA1, gB0, gB1, bA0, bA1, bB0, bB1;
        gA0.v = *(const half8*)&g1h[16 * p];        bA0.v = *(const half8*)&be1h[16 * p];
        gA1.v = *(const half8*)&g1h[16 * p + 8];    bA1.v = *(const half8*)&be1h[16 * p + 8];
        gB0.v = *(const half8*)&g1h[128 + 16 * p];  bB0.v = *(const half8*)&be1h[128 + 16 * p];
        gB1.v = *(const half8*)&g1h[136 + 16 * p];  bB1.v = *(const half8*)&be1h[136 + 16 * p];

        norm_gelu8(u0, gA0, bA0, rsh, nmuh);
        norm_gelu8(u1, gA1, bA1, rsh, nmuh);
        norm_gelu8(u2, gB0, bB0, rsh, nmuh);
        norm_gelu8(u3, gB1, bB1, rsh, nmuh);

        *(half8*)hrow0       = u0.v;
        *(half8*)(hrow0 + 8) = u1.v;
        *(half8*)hrow1       = u2.v;
        *(half8*)(hrow1 + 8) = u3.v;
    }
    __syncthreads();

    // ---- GEMM2: W2^T as A, H as B ----
    #pragma unroll
    for (int mt = 0; mt < 2; ++mt)
        #pragma unroll
        for (int nt = 0; nt < 4; ++nt)
            acc[mt][nt] = (f32x4){0.f, 0.f, 0.f, 0.f};

    #pragma unroll
    for (int kt = 0; kt < 8; ++kt) {
        const half8 h0 = *(const half8*)&H16[l15][kt * 32 + quad * 8];
        const half8 h1 = *(const half8*)&H16[16 + l15][kt * 32 + quad * 8];
        #pragma unroll
        for (int nt = 0; nt < 4; ++nt) {
            const half8 wf = *(const half8*)(w2w + (kt * 16 + nt) * 512 + lo8);
            acc[0][nt] = __builtin_amdgcn_mfma_f32_16x16x32_f16(wf, h0, acc[0][nt], 0, 0, 0);
            acc[1][nt] = __builtin_amdgcn_mfma_f32_16x16x32_f16(wf, h1, acc[1][nt], 0, 0, 0);
        }
    }
    __syncthreads();   // ALL B-reads of H16 done before in-place C-store

    // ---- C-store GEMM2: +b2, raw f16, contiguous b64 (acc dies here) ----
    #pragma unroll
    for (int nt = 0; nt < 4; ++nt) {
        const int chb = (w * 4 + nt) * 16 + quad * 4;
        const f32x4 bv = *(const f32x4*)&b2[chb];
        #pragma unroll
        for (int mt = 0; mt < 2; ++mt) {
            half4v h;
            #pragma unroll
            for (int r = 0; r < 4; ++r)
                h[r] = (_Float16)(acc[mt][nt][r] + bv[r]);
            *(half4v*)&H16[mt * 16 + l15][chb] = h;
        }
    }
    __syncthreads();

    // ---- Phase 5: LN2 (no activation), in place on H16 ----
    {
        H8u u0, u1, u2, u3;
        u0.v = *(const half8*)hrow0;
        u1.v = *(const half8*)(hrow0 + 8);
        u2.v = *(const half8*)hrow1;
        u3.v = *(const half8*)(hrow1 + 8);

        float s = 0.0f, s2 = 0.0f;
        stat8(u0, ones, s, s2); stat8(u1, ones, s, s2);
        stat8(u2, ones, s, s2); stat8(u3, ones, s, s2);
        #pragma unroll
        for (int off = 1; off < 8; off <<= 1) {
            s  += __shfl_xor(s, off, 64);
            s2 += __shfl_xor(s2, off, 64);
        }
        const float mu  = s * (1.0f / 256.0f);
        const float var = fmaf(s2, 1.0f / 256.0f, -mu * mu);
        const float rs  = __builtin_amdgcn_rsqf(var + 1e-5f);
        half2t rsh, nmuh;
        rsh[0]  = (_Float16)rs;    rsh[1]  = (_Float16)rs;
        nmuh[0] = (_Float16)(-mu); nmuh[1] = (_Float16)(-mu);

        H8u gA0, gA1, gB0, gB1, bA0, bA1, bB0, bB1;
        gA0.v = *(const half8*)&g2h[16 * p];        bA0.v = *(const half8*)&be2h[16 * p];
        gA1.v = *(const half8*)&g2h[16 * p + 8];    bA1.v = *(const half8*)&be2h[16 * p + 8];
        gB0.v = *(const half8*)&g2h[128 + 16 * p];  bB0.v = *(const half8*)&be2h[128 + 16 * p];
        gB1.v = *(const half8*)&g2h[136 + 16 * p];  bB1.v = *(const half8*)&be2h[136 + 16 * p];

        norm8(u0, gA0, bA0, rsh, nmuh);
        norm8(u1, gA1, bA1, rsh, nmuh);
        norm8(u2, gB0, bB0, rsh, nmuh);
        norm8(u3, gB1, bB1, rsh, nmuh);

        *(half8*)hrow0       = u0.v;
        *(half8*)(hrow0 + 8) = u1.v;
        *(half8*)hrow1       = u2.v;
        *(half8*)(hrow1 + 8) = u3.v;
    }
    __syncthreads();

    // ---- Phase 6: packed max over 32 points, coalesced float2 store ----
    if (t < 128) {
        const _Float16* Hf = &H16[0][0];
        half2t mx = *(const half2t*)(Hf + 2 * t);
        #pragma unroll
        for (int r = 1; r < KN; ++r) {
            const half2t v = *(const half2t*)(Hf + r * HSTR + 2 * t);
            mx = __builtin_elementwise_max(mx, v);
        }
        float2 o2;
        o2.x = (float)mx[0];
        o2.y = (float)mx[1];
        *(float2*)&out0[(size_t)q * C + 2 * t] = o2;
    }
}

extern "C" void kernel_launch(void* const* d_in, const int* in_sizes, int n_in,
                              void* d_out, int out_size, void* d_ws, size_t ws_size,
                              hipStream_t stream) {
    const float* xyz = (const float*)d_in[0];
    const float* pf  = (const float*)d_in[1];
    const float* ctr = (const float*)d_in[2];
    const float* W1  = (const float*)d_in[3];
    const float* b1  = (const float*)d_in[4];
    const float* g1  = (const float*)d_in[5];
    const float* be1 = (const float*)d_in[6];
    const float* W2  = (const float*)d_in[7];
    const float* b2  = (const float*)d_in[8];
    const float* g2  = (const float*)d_in[9];
    const float* be2 = (const float*)d_in[10];

    float* out = (float*)d_out;
    _Float16* wp = (_Float16*)d_ws;
    float4* xyzw = (float4*)(wp + WP_ELEMS);   // 180224 B offset, 16-aligned; +2 MB

    prep_kernel<<<(WP_ELEMS + NPTS * 8) / 256, 256, 0, stream>>>(W1, b1, W2, xyz, wp, xyzw);
    encoder_fused<<<NQ, 256, 0, stream>>>(xyzw, pf, ctr,
                                          g1, be1, b2, g2, be2,
                                          wp, wp + W1P_ELEMS,
                                          out, out + PF_ELEMS);
}